// Round 16
// baseline (353.356 us; speedup 1.0000x reference)
//
#include <hip/hip_runtime.h>

// Scaled-dot-product attention, bs=4, h=16, S=2048, D=64, f32 in/out.
// Outputs O [64,2048,64] and P=attn_weights [64,2048,2048] (f32, 1.07 GB write).
// Confirmed levers: full-128B-line stores (R7 +13%); nt full-line stores
// bypassing L2 write-allocate (R10 +25%); 2-tile/wave pipeline (R14 +13%).
// Nulls: reg prefetch (R5/R6/R15), wave specialization (R13 regression),
// store batching width pre-/post-nt (R9/R12), occupancy 4-vs-3 blocks (R11).
// R16: reduce per-iteration serialization. j-step 64 (24 MFMA + 8 stores per
// iter), P store DEFERRED one iteration via double-buffered LDS panel (stores
// issue during next iter's load window, off the exp->store tail; loads pinned
// older than stores), cleaner 16-slot XOR LDS mapping (baseline bank touches).

#define S_LEN 2048
#define DH 64
#define NHEADS 64  // bs*h

typedef short short8 __attribute__((ext_vector_type(8)));   // 8 x bf16
typedef float f32x4 __attribute__((ext_vector_type(4)));
typedef float f32x16 __attribute__((ext_vector_type(16)));
typedef unsigned short u16;

__device__ __forceinline__ u16 f2bf(float f) {
  union { float f; unsigned u; } x;
  x.f = f;
  unsigned r = x.u + 0x7fffu + ((x.u >> 16) & 1u);  // RNE
  return (u16)(r >> 16);
}

__device__ __forceinline__ unsigned pkbf(float a, float b) {
  return (unsigned)f2bf(a) | ((unsigned)f2bf(b) << 16);
}

// v_permlane32_swap_b32: new a[32+i]=old b[i]; new b[i]=old a[32+i]
__device__ __forceinline__ void plswap(unsigned& a, unsigned& b) {
  asm("v_permlane32_swap_b32 %0, %1" : "+v"(a), "+v"(b));
}

__device__ __forceinline__ f32x16 qk4(short8 k0, short8 k1, short8 k2, short8 k3,
                                      short8 w0, short8 w1, short8 w2, short8 w3) {
  f32x16 s = {};
  s = __builtin_amdgcn_mfma_f32_32x32x16_bf16(k0, w0, s, 0, 0, 0);
  s = __builtin_amdgcn_mfma_f32_32x32x16_bf16(k1, w1, s, 0, 0, 0);
  s = __builtin_amdgcn_mfma_f32_32x32x16_bf16(k2, w2, s, 0, 0, 0);
  s = __builtin_amdgcn_mfma_f32_32x32x16_bf16(k3, w3, s, 0, 0, 0);
  return s;
}

// T12 redistribute: D-layout p[16] -> two A-frags (k = hi*8+i contiguous j)
__device__ __forceinline__ void packPA(const f32x16& p, short8& f0, short8& f1) {
  unsigned A0 = pkbf(p[0], p[1]),   A1 = pkbf(p[2], p[3]);
  unsigned B0 = pkbf(p[4], p[5]),   B1 = pkbf(p[6], p[7]);
  plswap(A0, B0);
  plswap(A1, B1);
  unsigned C0 = pkbf(p[8], p[9]),   C1 = pkbf(p[10], p[11]);
  unsigned D0 = pkbf(p[12], p[13]), D1 = pkbf(p[14], p[15]);
  plswap(C0, D0);
  plswap(C1, D1);
  union { unsigned w[4]; short8 v; } u0 = {{A0, A1, B0, B1}};
  union { unsigned w[4]; short8 v; } u1 = {{C0, C1, D0, D1}};
  f0 = u0.v;
  f1 = u1.v;
}

// transposed panel write: lane q holds chunks cbase+2g+hi of its 64-j row
__device__ __forceinline__ void twrite(float* t, const f32x16& p, int q, int hi,
                                       int cbase) {
#pragma unroll
  for (int g = 0; g < 4; ++g) {
    int c = cbase + 2 * g + hi;
    int phys = c ^ (q & 15);
    f32x4 w = {p[4 * g], p[4 * g + 1], p[4 * g + 2], p[4 * g + 3]};
    *(f32x4*)&t[q * 64 + phys * 4] = w;
  }
}

// full-line nt burst: 32 rows x 256B from a [32][64] XOR-swizzled panel
__device__ __forceinline__ void pstore(const float* t, float* gb, int gstride,
                                       int l4, int rc16) {
#pragma unroll
  for (int g = 0; g < 8; ++g) {
    int qi = 4 * g + l4;
    int phys = rc16 ^ (qi & 15);
    f32x4 v = *(const f32x4*)&t[qi * 64 + phys * 4];
    __builtin_nontemporal_store(v, (f32x4*)(gb + (size_t)qi * gstride + rc16 * 4));
  }
}

// ---- pre-pass: Q * scale -> bf16, same layout ----
__global__ __launch_bounds__(256) void cvt_scale_k(const float* __restrict__ in,
                                                   u16* __restrict__ out,
                                                   float scale, int n4) {
  int i = blockIdx.x * 256 + threadIdx.x;
  if (i >= n4) return;
  float4 v = ((const float4*)in)[i];
  union { u16 s[4]; unsigned long long ll; } o;
  o.s[0] = f2bf(v.x * scale); o.s[1] = f2bf(v.y * scale);
  o.s[2] = f2bf(v.z * scale); o.s[3] = f2bf(v.w * scale);
  ((unsigned long long*)out)[i] = o.ll;
}

// ---- pre-pass: per-head transpose [R][C] f32 -> [C][R] bf16 ----
__global__ __launch_bounds__(256) void transpose_cvt_k(const float* __restrict__ in,
                                                       u16* __restrict__ out,
                                                       int R, int C) {
  __shared__ float tile[64][65];
  const int tilesC = C >> 6;
  const int tilesPerHead = (R >> 6) * tilesC;
  int hb = blockIdx.x;
  int head = hb / tilesPerHead;
  int t = hb - head * tilesPerHead;
  int tr = t / tilesC, tc = t - tr * tilesC;
  const float* ip = in + (size_t)head * R * C + (size_t)tr * 64 * C + (size_t)tc * 64;
  u16* op = out + (size_t)head * R * C + (size_t)tc * 64 * R + (size_t)tr * 64;
  int c = threadIdx.x & 63, r0 = threadIdx.x >> 6;
#pragma unroll
  for (int k = 0; k < 16; ++k) {
    int r = (k << 2) + r0;
    tile[r][c] = ip[(size_t)r * C + c];
  }
  __syncthreads();
#pragma unroll
  for (int k = 0; k < 16; ++k) {
    int orow = (k << 2) + r0;
    op[(size_t)orow * R + c] = f2bf(tile[c][orow]);
  }
}

// ---- fused attention: 2-tile/wave, j-step 64, deferred nt burst stores ----
// Layouts (bf16): Qb [h][s][d] (pre-scaled), Kn [h][s][d], Vt [h][d][s].
// Block = 4 waves x (tiles A,B of 32 rows); phases [p1A][p2A+p1B][p2B].
// mfma_f32_32x32x16_bf16:  A row=lane&31, k=(lane>>5)*8+i (8 contig)
//                          B col=lane&31, k=(lane>>5)*8+i
//                          D col=lane&31, row=(r&3)+8*(r>>2)+4*(lane>>5)
__global__ __launch_bounds__(256, 2) void attn_k(const u16* __restrict__ Qb,
                                                 const u16* __restrict__ Kn,
                                                 const u16* __restrict__ Vt,
                                                 float* __restrict__ Og,
                                                 float* __restrict__ Pg) {
  __shared__ float buf[4][2][32 * 64];  // per-wave double-buffered 32x64 panel
  int bid = blockIdx.x;
  // bijective XCD swizzle: 512 blocks, XCD x gets heads 8x..8x+7
  int work = ((bid & 7) << 6) | (bid >> 3);
  int head = work >> 3;
  int rblk = work & 7;
  int lane = threadIdx.x & 63;
  int wv = threadIdx.x >> 6;
  int q = lane & 31;
  int hi = lane >> 5;
  int q0A = (rblk << 8) + (wv << 5);
  int q0B = q0A + 128;
  int l4 = lane >> 4;    // 0..3: row-in-group for burst stores
  int rc16 = lane & 15;  // 0..15: 16B chunk within the 256B row span

  const u16* qpA = Qb + (size_t)(head * S_LEN + q0A + q) * DH + hi * 8;
  short8 qa0 = *(const short8*)(qpA);
  short8 qa1 = *(const short8*)(qpA + 16);
  short8 qa2 = *(const short8*)(qpA + 32);
  short8 qa3 = *(const short8*)(qpA + 48);
  const u16* qpB = Qb + (size_t)(head * S_LEN + q0B + q) * DH + hi * 8;
  short8 qb0 = *(const short8*)(qpB);
  short8 qb1 = *(const short8*)(qpB + 16);
  short8 qb2 = *(const short8*)(qpB + 32);
  short8 qb3 = *(const short8*)(qpB + 48);

  const u16* kp = Kn + (size_t)head * S_LEN * DH + (size_t)q * DH + hi * 8;
  const u16* vp = Vt + (size_t)head * DH * S_LEN + (size_t)q * S_LEN + hi * 8;

  // ---- phase 1: lA ----
  float la0 = 0.f, la1 = 0.f, la2 = 0.f, la3 = 0.f;
  for (int j0 = 0; j0 < S_LEN; j0 += 64) {
    const u16* kbA = kp + (size_t)j0 * DH;
    short8 ka0 = *(const short8*)(kbA),      ka1 = *(const short8*)(kbA + 16);
    short8 ka2 = *(const short8*)(kbA + 32), ka3 = *(const short8*)(kbA + 48);
    const u16* kbB = kp + (size_t)(j0 + 32) * DH;
    short8 kb0 = *(const short8*)(kbB),      kb1 = *(const short8*)(kbB + 16);
    short8 kb2 = *(const short8*)(kbB + 32), kb3 = *(const short8*)(kbB + 48);
    f32x16 sl = qk4(ka0, ka1, ka2, ka3, qa0, qa1, qa2, qa3);
    f32x16 sh = qk4(kb0, kb1, kb2, kb3, qa0, qa1, qa2, qa3);
#pragma unroll
    for (int r = 0; r < 16; r += 4) {
      la0 += __expf(sl[r]) + __expf(sh[r]);
      la1 += __expf(sl[r + 1]) + __expf(sh[r + 1]);
      la2 += __expf(sl[r + 2]) + __expf(sh[r + 2]);
      la3 += __expf(sl[r + 3]) + __expf(sh[r + 3]);
    }
  }
  float lsA = (la0 + la1) + (la2 + la3);
  lsA += __shfl_xor(lsA, 32);
  float rlA = 1.f / lsA;

  // ---- phase 2: pass2(A) + pass1(B), K shared, stores deferred 1 iter ----
  f32x16 oa = {}, ob = {};
  float lb0 = 0.f, lb1 = 0.f, lb2 = 0.f, lb3 = 0.f;
  float* pbA = Pg + (size_t)(head * S_LEN + q0A) * S_LEN;

  for (int j0 = 0; j0 < S_LEN; j0 += 64) {
    int cur = (j0 >> 6) & 1;
    const u16* kbA = kp + (size_t)j0 * DH;
    short8 ka0 = *(const short8*)(kbA),      ka1 = *(const short8*)(kbA + 16);
    short8 ka2 = *(const short8*)(kbA + 32), ka3 = *(const short8*)(kbA + 48);
    const u16* kbB = kp + (size_t)(j0 + 32) * DH;
    short8 kb0 = *(const short8*)(kbB),      kb1 = *(const short8*)(kbB + 16);
    short8 kb2 = *(const short8*)(kbB + 32), kb3 = *(const short8*)(kbB + 48);
    const u16* vjA = vp + j0;
    short8 va0 = *(const short8*)(vjA),      va1 = *(const short8*)(vjA + 16);
    short8 va2 = *(const short8*)(vjA + 32 * S_LEN);
    short8 va3 = *(const short8*)(vjA + 32 * S_LEN + 16);
    const u16* vjB = vp + j0 + 32;
    short8 vb0 = *(const short8*)(vjB),      vb1 = *(const short8*)(vjB + 16);
    short8 vb2 = *(const short8*)(vjB + 32 * S_LEN);
    short8 vb3 = *(const short8*)(vjB + 32 * S_LEN + 16);
    __builtin_amdgcn_sched_barrier(0);  // loads above stay OLDER than stores below

    if (j0)  // deferred store of previous panel (issues in load-latency window)
      pstore(&buf[wv][cur ^ 1][0], pbA + j0 - 64, S_LEN, l4, rc16);

    f32x16 sl = qk4(ka0, ka1, ka2, ka3, qa0, qa1, qa2, qa3);
    f32x16 sh = qk4(kb0, kb1, kb2, kb3, qa0, qa1, qa2, qa3);
    f32x16 pl, ph;
#pragma unroll
    for (int r = 0; r < 16; ++r) {
      pl[r] = __expf(sl[r]) * rlA;
      ph[r] = __expf(sh[r]) * rlA;
    }
    float* tc = &buf[wv][cur][0];
    twrite(tc, pl, q, hi, 0);
    twrite(tc, ph, q, hi, 8);

    short8 pa0, pa1, pa2, pa3;
    packPA(pl, pa0, pa1);
    packPA(ph, pa2, pa3);
    oa = __builtin_amdgcn_mfma_f32_32x32x16_bf16(pa0, va0, oa, 0, 0, 0);
    oa = __builtin_amdgcn_mfma_f32_32x32x16_bf16(pa1, va1, oa, 0, 0, 0);
    oa = __builtin_amdgcn_mfma_f32_32x32x16_bf16(pa2, vb0, oa, 0, 0, 0);
    oa = __builtin_amdgcn_mfma_f32_32x32x16_bf16(pa3, vb1, oa, 0, 0, 0);
    ob = __builtin_amdgcn_mfma_f32_32x32x16_bf16(pa0, va2, ob, 0, 0, 0);
    ob = __builtin_amdgcn_mfma_f32_32x32x16_bf16(pa1, va3, ob, 0, 0, 0);
    ob = __builtin_amdgcn_mfma_f32_32x32x16_bf16(pa2, vb2, ob, 0, 0, 0);
    ob = __builtin_amdgcn_mfma_f32_32x32x16_bf16(pa3, vb3, ob, 0, 0, 0);

    // pass1(B) on the SAME K registers
    f32x16 t1 = qk4(ka0, ka1, ka2, ka3, qb0, qb1, qb2, qb3);
    f32x16 t2 = qk4(kb0, kb1, kb2, kb3, qb0, qb1, qb2, qb3);
#pragma unroll
    for (int r = 0; r < 16; r += 4) {
      lb0 += __expf(t1[r]) + __expf(t2[r]);
      lb1 += __expf(t1[r + 1]) + __expf(t2[r + 1]);
      lb2 += __expf(t1[r + 2]) + __expf(t2[r + 2]);
      lb3 += __expf(t1[r + 3]) + __expf(t2[r + 3]);
    }
  }
  pstore(&buf[wv][1][0], pbA + S_LEN - 64, S_LEN, l4, rc16);  // last panel (cur=1)

  // ---- O_A epilogue via panel (buf 0 free) ----
  {
    float* te = &buf[wv][0][0];
#pragma unroll
    for (int r = 0; r < 16; ++r) {
      int row = (r & 3) + 8 * (r >> 2) + 4 * hi;
      te[row * 64 + (((q >> 2) ^ (row & 15)) << 2) + (q & 3)] = oa[r];
      int d2 = q + 32;
      te[row * 64 + (((d2 >> 2) ^ (row & 15)) << 2) + (d2 & 3)] = ob[r];
    }
    pstore(te, Og + (size_t)(head * S_LEN + q0A) * DH, DH, l4, rc16);
  }

  float lsB = (lb0 + lb1) + (lb2 + lb3);
  lsB += __shfl_xor(lsB, 32);
  float rlB = 1.f / lsB;

  // ---- phase 3: pass2(B), stores deferred 1 iter ----
  oa = (f32x16){};
  ob = (f32x16){};
  float* pbB = Pg + (size_t)(head * S_LEN + q0B) * S_LEN;

  for (int j0 = 0; j0 < S_LEN; j0 += 64) {
    int cur = (j0 >> 6) & 1;
    const u16* kbA = kp + (size_t)j0 * DH;
    short8 ka0 = *(const short8*)(kbA),      ka1 = *(const short8*)(kbA + 16);
    short8 ka2 = *(const short8*)(kbA + 32), ka3 = *(const short8*)(kbA + 48);
    const u16* kbB = kp + (size_t)(j0 + 32) * DH;
    short8 kb0 = *(const short8*)(kbB),      kb1 = *(const short8*)(kbB + 16);
    short8 kb2 = *(const short8*)(kbB + 32), kb3 = *(const short8*)(kbB + 48);
    const u16* vjA = vp + j0;
    short8 va0 = *(const short8*)(vjA),      va1 = *(const short8*)(vjA + 16);
    short8 va2 = *(const short8*)(vjA + 32 * S_LEN);
    short8 va3 = *(const short8*)(vjA + 32 * S_LEN + 16);
    const u16* vjB = vp + j0 + 32;
    short8 vb0 = *(const short8*)(vjB),      vb1 = *(const short8*)(vjB + 16);
    short8 vb2 = *(const short8*)(vjB + 32 * S_LEN);
    short8 vb3 = *(const short8*)(vjB + 32 * S_LEN + 16);
    __builtin_amdgcn_sched_barrier(0);

    if (j0)
      pstore(&buf[wv][cur ^ 1][0], pbB + j0 - 64, S_LEN, l4, rc16);

    f32x16 sl = qk4(ka0, ka1, ka2, ka3, qb0, qb1, qb2, qb3);
    f32x16 sh = qk4(kb0, kb1, kb2, kb3, qb0, qb1, qb2, qb3);
    f32x16 pl, ph;
#pragma unroll
    for (int r = 0; r < 16; ++r) {
      pl[r] = __expf(sl[r]) * rlB;
      ph[r] = __expf(sh[r]) * rlB;
    }
    float* tc = &buf[wv][cur][0];
    twrite(tc, pl, q, hi, 0);
    twrite(tc, ph, q, hi, 8);

    short8 pa0, pa1, pa2, pa3;
    packPA(pl, pa0, pa1);
    packPA(ph, pa2, pa3);
    oa = __builtin_amdgcn_mfma_f32_32x32x16_bf16(pa0, va0, oa, 0, 0, 0);
    oa = __builtin_amdgcn_mfma_f32_32x32x16_bf16(pa1, va1, oa, 0, 0, 0);
    oa = __builtin_amdgcn_mfma_f32_32x32x16_bf16(pa2, vb0, oa, 0, 0, 0);
    oa = __builtin_amdgcn_mfma_f32_32x32x16_bf16(pa3, vb1, oa, 0, 0, 0);
    ob = __builtin_amdgcn_mfma_f32_32x32x16_bf16(pa0, va2, ob, 0, 0, 0);
    ob = __builtin_amdgcn_mfma_f32_32x32x16_bf16(pa1, va3, ob, 0, 0, 0);
    ob = __builtin_amdgcn_mfma_f32_32x32x16_bf16(pa2, vb2, ob, 0, 0, 0);
    ob = __builtin_amdgcn_mfma_f32_32x32x16_bf16(pa3, vb3, ob, 0, 0, 0);
  }
  pstore(&buf[wv][1][0], pbB + S_LEN - 64, S_LEN, l4, rc16);

  // ---- O_B epilogue ----
  {
    float* te = &buf[wv][0][0];
#pragma unroll
    for (int r = 0; r < 16; ++r) {
      int row = (r & 3) + 8 * (r >> 2) + 4 * hi;
      te[row * 64 + (((q >> 2) ^ (row & 15)) << 2) + (q & 3)] = oa[r];
      int d2 = q + 32;
      te[row * 64 + (((d2 >> 2) ^ (row & 15)) << 2) + (d2 & 3)] = ob[r];
    }
    pstore(te, Og + (size_t)(head * S_LEN + q0B) * DH, DH, l4, rc16);
  }
}

extern "C" void kernel_launch(void* const* d_in, const int* in_sizes, int n_in,
                              void* d_out, int out_size, void* d_ws, size_t ws_size,
                              hipStream_t stream) {
  const float* q = (const float*)d_in[0];
  const float* k = (const float*)d_in[1];  // [b,h,d,s]
  const float* v = (const float*)d_in[2];  // [b,h,s,d]
  float* Og = (float*)d_out;
  float* Pg = Og + (size_t)NHEADS * S_LEN * DH;

  const size_t elems = (size_t)NHEADS * S_LEN * DH;  // 8,388,608
  u16* Qb = (u16*)d_ws;           // bf16 [h][s][d], pre-scaled
  u16* Kn = Qb + elems;           // bf16 [h][s][d]
  u16* Vt = Kn + elems;           // bf16 [h][d][s]

  int n4 = (int)(elems / 4);
  cvt_scale_k<<<n4 / 256, 256, 0, stream>>>(q, Qb, 0.125f, n4);
  transpose_cvt_k<<<NHEADS * (S_LEN / 64), 256, 0, stream>>>(k, Kn, DH, S_LEN);
  transpose_cvt_k<<<NHEADS * (S_LEN / 64), 256, 0, stream>>>(v, Vt, S_LEN, DH);
  attn_k<<<NHEADS * (S_LEN / 256), 256, 0, stream>>>(Qb, Kn, Vt, Og, Pg);
}